// Round 10
// baseline (189.896 us; speedup 1.0000x reference)
//
#include <hip/hip_runtime.h>
#include <hip/hip_bf16.h>

typedef __attribute__((ext_vector_type(8))) short bf16x8;
typedef __attribute__((ext_vector_type(4))) float f32x4;
typedef __attribute__((ext_vector_type(2))) float f32x2;
typedef __attribute__((ext_vector_type(2))) unsigned int u32x2;

#define IN_DIM 128
#define OUT_DIM 256
#define CHUNK 4096
#define CHUNK2 2048

__device__ __forceinline__ short f2bf(float f) {
    __hip_bfloat16 t = __float2bfloat16(f);
    return __builtin_bit_cast(short, t);
}

// decode 8 fp8 (u32x2) -> accumulate into 4x f32x2
__device__ __forceinline__ void accumf8(f32x2* a, u32x2 v) {
    f32x2 p0 = __builtin_amdgcn_cvt_pk_f32_fp8(v[0], false);
    f32x2 p1 = __builtin_amdgcn_cvt_pk_f32_fp8(v[0], true);
    f32x2 p2 = __builtin_amdgcn_cvt_pk_f32_fp8(v[1], false);
    f32x2 p3 = __builtin_amdgcn_cvt_pk_f32_fp8(v[1], true);
    a[0] += p0; a[1] += p1; a[2] += p2; a[3] += p3;
}

// ---------------- fused: bucket count + W prep + x->bf16 + x->fp8 ----------------
__global__ void k_prep(const int* __restrict__ edst, int* __restrict__ gcnt, int E,
                       int nEB, int NB,
                       const float* __restrict__ x, __hip_bfloat16* __restrict__ xb,
                       unsigned char* __restrict__ xf8, int nxelem,
                       const float* __restrict__ W, __hip_bfloat16* __restrict__ wt) {
    __shared__ int cnt[512];
    int b = blockIdx.x;
    int tid = threadIdx.x;
    if (b < nEB) {
        for (int i = tid; i < NB; i += 256) cnt[i] = 0;
        __syncthreads();
        int e0 = b * CHUNK;
        int eend = min(e0 + CHUNK, E);
        for (int i = e0 + tid; i < eend; i += 256) atomicAdd(&cnt[edst[i] >> 8], 1);
        __syncthreads();
        for (int i = tid; i < NB; i += 256) if (cnt[i]) atomicAdd(&gcnt[i], cnt[i]);
    } else if (b < nEB + 256) {
        // wt layout: [half(2)][col_local(128)][k(256)] bf16, byte XOR-swizzled
        int i = (b - nEB) * 256 + tid;   // i = k*256 + col
        int k = i >> 8, col = i & 255;
        int half = col >> 7, cl = col & 127;
        int byte = half * 65536 + cl * 512 + ((2 * k) ^ ((cl & 7) << 4));
        wt[byte >> 1] = __float2bfloat16(W[i]);
    } else {
        int i = (b - nEB - 256) * 256 + tid;   // 8 elems/thread
        size_t e0 = (size_t)i * 8;
        if (e0 < (size_t)nxelem) {
            const float4* xf4 = (const float4*)x;
            float4 v0 = xf4[i * 2], v1 = xf4[i * 2 + 1];
            bf16x8 o;
            o[0] = f2bf(v0.x); o[1] = f2bf(v0.y); o[2] = f2bf(v0.z); o[3] = f2bf(v0.w);
            o[4] = f2bf(v1.x); o[5] = f2bf(v1.y); o[6] = f2bf(v1.z); o[7] = f2bf(v1.w);
            *(bf16x8*)(xb + e0) = o;
            unsigned w0 = 0, w1 = 0;
            w0 = __builtin_amdgcn_cvt_pk_fp8_f32(v0.x, v0.y, w0, false);
            w0 = __builtin_amdgcn_cvt_pk_fp8_f32(v0.z, v0.w, w0, true);
            w1 = __builtin_amdgcn_cvt_pk_fp8_f32(v1.x, v1.y, w1, false);
            w1 = __builtin_amdgcn_cvt_pk_fp8_f32(v1.z, v1.w, w1, true);
            u32x2 pk; pk[0] = w0; pk[1] = w1;
            *(u32x2*)(xf8 + e0) = pk;
        }
    }
}

// ---------------- one-block parallel scan over buckets ----------------
__global__ void k_scan_nb(const int* __restrict__ gcnt, int* __restrict__ gbase,
                          int* __restrict__ gcur, int NB) {
    __shared__ int tmp[512];
    int t = threadIdx.x;
    int v = (t < NB) ? gcnt[t] : 0;
    tmp[t] = v;
    __syncthreads();
    for (int off = 1; off < 512; off <<= 1) {
        int add = (t >= off) ? tmp[t - off] : 0;
        __syncthreads();
        tmp[t] += add;
        __syncthreads();
    }
    int excl = tmp[t] - v;
    if (t < NB) { gbase[t] = excl; gcur[t] = excl; }
    if (t == 511) gbase[NB] = tmp[511];
}

// ---------------- pass A2: packed (src<<8|dstlo) pairs, 2048-edge chunks ----------------
__global__ void k_binA_write(const int* __restrict__ esrc, const int* __restrict__ edst,
                             int* __restrict__ gcur, unsigned int* __restrict__ pairs,
                             int E, int NB) {
    __shared__ int cnt[512];
    __shared__ int base[512];
    int t = threadIdx.x;
    for (int b = t; b < NB; b += 256) cnt[b] = 0;
    __syncthreads();
    int e0 = blockIdx.x * CHUNK2;
    int eend = min(e0 + CHUNK2, E);
    for (int i = e0 + t; i < eend; i += 256) atomicAdd(&cnt[edst[i] >> 8], 1);
    __syncthreads();
    for (int b = t; b < NB; b += 256) {
        base[b] = cnt[b] ? atomicAdd(&gcur[b], cnt[b]) : 0;
        cnt[b] = 0;
    }
    __syncthreads();
    for (int i = e0 + t; i < eend; i += 256) {
        int d = edst[i];
        int b = d >> 8;
        int idx = atomicAdd(&cnt[b], 1);
        pairs[base[b] + idx] = ((unsigned)esrc[i] << 8) | (unsigned)(d & 255);
    }
}

// ---------------- pass B: one block per bucket -> offs + csr ----------------
__global__ void k_binB(const unsigned int* __restrict__ pairs, const int* __restrict__ gbase,
                       int* __restrict__ offs, int* __restrict__ csr, int n) {
    __shared__ int cnt[256];
    __shared__ int tmp[256];
    int t = threadIdx.x;
    int b = blockIdx.x;
    int node0 = b << 8;
    cnt[t] = 0;
    __syncthreads();
    int beg = gbase[b], end = gbase[b + 1];
    for (int i = beg + t; i < end; i += 256) atomicAdd(&cnt[pairs[i] & 255], 1);
    __syncthreads();
    int v = cnt[t];
    tmp[t] = v;
    __syncthreads();
    for (int off = 1; off < 256; off <<= 1) {
        int add = (t >= off) ? tmp[t - off] : 0;
        __syncthreads();
        tmp[t] += add;
        __syncthreads();
    }
    int excl = tmp[t] - v;
    int node = node0 + t;
    if (node <= n) offs[node] = beg + excl;
    cnt[t] = beg + excl;
    __syncthreads();
    for (int i = beg + t; i < end; i += 256) {
        unsigned p = pairs[i];
        int slot = atomicAdd(&cnt[p & 255], 1);
        csr[slot] = (int)(p >> 8);
    }
}

// ---------------- aggregate: fp8 gather, one wave per node, 4 groups x 16 lanes ----------------
__global__ __launch_bounds__(256) void k_aggregate(const unsigned char* __restrict__ xf8,
                                                   const __hip_bfloat16* __restrict__ xb,
                                                   const int* __restrict__ offs,
                                                   const int* __restrict__ csr,
                                                   __hip_bfloat16* __restrict__ aggb, int n) {
    int tid = threadIdx.x;
    int node = blockIdx.x * 4 + (tid >> 6);
    if (node >= n) return;
    int lane = tid & 63;
    int g = lane >> 4;         // 0..3
    int l = lane & 15;         // 8B chunk within 128B row
    int beg = offs[node], end = offs[node + 1];
    int d = end - beg;
    const char* xbase = (const char*)xf8;    // row = src*128 bytes
    unsigned loff = (unsigned)(l << 3);

    f32x2 acc[4];   // dims 8l .. 8l+7
#pragma unroll
    for (int i = 0; i < 4; i++) acc[i] = (f32x2){0.f, 0.f};

    int j = beg + g;
    for (; j + 12 < end; j += 16) {
        u32x2 v0 = *(const u32x2*)(xbase + (((unsigned)csr[j] << 7) + loff));
        u32x2 v1 = *(const u32x2*)(xbase + (((unsigned)csr[j + 4] << 7) + loff));
        u32x2 v2 = *(const u32x2*)(xbase + (((unsigned)csr[j + 8] << 7) + loff));
        u32x2 v3 = *(const u32x2*)(xbase + (((unsigned)csr[j + 12] << 7) + loff));
        accumf8(acc, v0); accumf8(acc, v1); accumf8(acc, v2); accumf8(acc, v3);
    }
    {
        u32x2 z = (u32x2){0, 0};
        u32x2 t0 = z, t1 = z, t2 = z;
        if (j < end)     t0 = *(const u32x2*)(xbase + (((unsigned)csr[j] << 7) + loff));
        if (j + 4 < end) t1 = *(const u32x2*)(xbase + (((unsigned)csr[j + 4] << 7) + loff));
        if (j + 8 < end) t2 = *(const u32x2*)(xbase + (((unsigned)csr[j + 8] << 7) + loff));
        accumf8(acc, t0); accumf8(acc, t1); accumf8(acc, t2);
    }

#pragma unroll
    for (int u = 0; u < 4; u++) {
        float a = acc[u].x, b = acc[u].y;
        a += __shfl_xor(a, 16); b += __shfl_xor(b, 16);
        a += __shfl_xor(a, 32); b += __shfl_xor(b, 32);
        acc[u].x = a; acc[u].y = b;
    }

    if (g == 0) {
        bf16x8 o;
        if (d > 0) {
            float inv = 1.0f / (float)d;
#pragma unroll
            for (int i = 0; i < 4; i++) {
                o[2 * i]     = f2bf(acc[i].x * inv);
                o[2 * i + 1] = f2bf(acc[i].y * inv);
            }
        } else {
            o = *(const bf16x8*)(xb + (size_t)node * 128 + l * 8);
        }
        *(bf16x8*)(aggb + (size_t)node * 128 + l * 8) = o;
    }
}

// ---------------- GEMM: BM=256, two BN=128 halves per block (A-panel L2 reuse) ----------------
// 256 thr (4 waves), 64KB LDS -> 2 blocks/CU; block loops wh=0,1 restaging W-half.
__global__ __launch_bounds__(256, 2) void k_gemm(const __hip_bfloat16* __restrict__ xb,
                                                 const __hip_bfloat16* __restrict__ aggb,
                                                 const __hip_bfloat16* __restrict__ wt,
                                                 const float* __restrict__ bias,
                                                 float* __restrict__ out, int n) {
    __shared__ uint4 lds4[4096];   // 64KB: one W half, swizzled [col][k]
    int tid = threadIdx.x;
    int row0 = blockIdx.x * 256;
    int wave = tid >> 6, lane = tid & 63;
    int colb = lane & 15, kgrp = lane >> 4;
    int swz = (colb & 7) << 4;
    int wrow0 = row0 + wave * 64;

    const bf16x8* hx[4];
    const bf16x8* hg[4];
#pragma unroll
    for (int m = 0; m < 4; m++) {
        int r = wrow0 + m * 16 + colb;
        int ar = r < n ? r : (n - 1);
        hx[m] = (const bf16x8*)(xb + (size_t)ar * 128);
        hg[m] = (const bf16x8*)(aggb + (size_t)ar * 128);
    }

    for (int wh = 0; wh < 2; wh++) {
        if (wh) __syncthreads();   // all reads of previous half done before restage
        const uint4* src = (const uint4*)((const char*)wt + wh * 65536);
        for (int i = tid; i < 4096; i += 256) lds4[i] = src[i];
        __syncthreads();

        f32x4 acc[4][8];
#pragma unroll
        for (int m = 0; m < 4; m++)
#pragma unroll
            for (int nf = 0; nf < 8; nf++) acc[m][nf] = (f32x4){0.f, 0.f, 0.f, 0.f};

        const char* ldsb = (const char*)lds4;
#pragma unroll
        for (int ks = 0; ks < 8; ks++) {
            bf16x8 a[4];
#pragma unroll
            for (int m = 0; m < 4; m++)
                a[m] = (ks < 4) ? hx[m][kgrp + ks * 4] : hg[m][kgrp + (ks - 4) * 4];
            int kbyte = (kgrp * 16 + ks * 64) ^ swz;
#pragma unroll
            for (int nf = 0; nf < 8; nf++) {
                bf16x8 bfrag = *(const bf16x8*)(ldsb + (nf * 16 + colb) * 512 + kbyte);
#pragma unroll
                for (int m = 0; m < 4; m++)
                    acc[m][nf] = __builtin_amdgcn_mfma_f32_16x16x32_bf16(bfrag, a[m], acc[m][nf], 0, 0, 0);
            }
        }

        // out row = wrow0 + m*16 + colb ; out col = wh*128 + nf*16 + kgrp*4 + i
#pragma unroll
        for (int m = 0; m < 4; m++) {
            int r = wrow0 + m * 16 + colb;
            if (r < n) {
                float* orow = out + (size_t)r * 256 + wh * 128;
#pragma unroll
                for (int nf = 0; nf < 8; nf++) {
                    int c0 = nf * 16 + kgrp * 4;
                    f32x4 bv = *(const f32x4*)(bias + wh * 128 + c0);
                    f32x4 v = acc[m][nf] + bv;
#pragma unroll
                    for (int i = 0; i < 4; i++) v[i] = v[i] > 0.f ? v[i] : 0.f;
                    *(f32x4*)(orow + c0) = v;
                }
            }
        }
    }
}

extern "C" void kernel_launch(void* const* d_in, const int* in_sizes, int n_in,
                              void* d_out, int out_size, void* d_ws, size_t ws_size,
                              hipStream_t stream) {
    const float* x    = (const float*)d_in[0];
    const int*   esrc = (const int*)d_in[1];
    const int*   edst = (const int*)d_in[2];
    const float* W    = (const float*)d_in[3];
    const float* bias = (const float*)d_in[4];
    float* out = (float*)d_out;

    int n = in_sizes[0] / IN_DIM;   // 100000
    int E = in_sizes[1];            // 1600000
    int nxelem = n * IN_DIM;
    int NB = (n + 255) >> 8;        // 391

    char* p = (char*)d_ws;
    auto alloc = [&](size_t bytes) {
        char* r = p;
        p += (bytes + 255) & ~(size_t)255;
        return r;
    };
    int* gcnt  = (int*)alloc((size_t)NB * 4);
    int* gbase = (int*)alloc((size_t)(NB + 1) * 4);
    int* gcur  = (int*)alloc((size_t)NB * 4);
    int* offs  = (int*)alloc((size_t)(n + 1) * 4);
    unsigned int* pairs = (unsigned int*)alloc((size_t)E * 4);
    int* csr   = (int*)alloc((size_t)E * 4);
    __hip_bfloat16* wt   = (__hip_bfloat16*)alloc((size_t)65536 * 2);
    __hip_bfloat16* xb   = (__hip_bfloat16*)alloc((size_t)nxelem * 2);
    __hip_bfloat16* aggb = (__hip_bfloat16*)alloc((size_t)nxelem * 2);
    unsigned char* xf8   = (unsigned char*)alloc((size_t)nxelem);

    int nEB = (E + CHUNK - 1) / CHUNK;           // 391 (count pass)
    int nEB2 = (E + CHUNK2 - 1) / CHUNK2;        // 782 (write pass)
    int xcastB = (nxelem / 8 + 255) / 256;       // 6250

    hipMemsetAsync(gcnt, 0, (size_t)NB * 4, stream);
    k_prep<<<nEB + 256 + xcastB, 256, 0, stream>>>(edst, gcnt, E, nEB, NB,
                                                   x, xb, xf8, nxelem, W, wt);
    k_scan_nb<<<1, 512, 0, stream>>>(gcnt, gbase, gcur, NB);
    k_binA_write<<<nEB2, 256, 0, stream>>>(esrc, edst, gcur, pairs, E, NB);
    k_binB<<<NB, 256, 0, stream>>>(pairs, gbase, offs, csr, n);
    k_aggregate<<<(n + 3) / 4, 256, 0, stream>>>(xf8, xb, offs, csr, aggb, n);
    k_gemm<<<(n + 255) / 256, 256, 0, stream>>>(xb, aggb, wt, bias, out, n);
}

// Round 11
// 186.908 us; speedup vs baseline: 1.0160x; 1.0160x over previous
//
#include <hip/hip_runtime.h>
#include <hip/hip_bf16.h>

typedef __attribute__((ext_vector_type(8))) short bf16x8;
typedef __attribute__((ext_vector_type(4))) float f32x4;
typedef __attribute__((ext_vector_type(2))) float f32x2;
typedef __attribute__((ext_vector_type(4))) unsigned int u32x4;
typedef __attribute__((ext_vector_type(2))) unsigned int u32x2;

#define IN_DIM 128
#define OUT_DIM 256
#define CHUNK 4096
#define CHUNK2 2048

__device__ __forceinline__ short f2bf(float f) {
    __hip_bfloat16 t = __float2bfloat16(f);
    return __builtin_bit_cast(short, t);
}

// decode 16 fp8 (u32x4) -> accumulate into 8x f32x2
__device__ __forceinline__ void accumf8x16(f32x2* a, u32x4 v) {
#pragma unroll
    for (int w = 0; w < 4; w++) {
        a[2 * w]     += __builtin_amdgcn_cvt_pk_f32_fp8(v[w], false);
        a[2 * w + 1] += __builtin_amdgcn_cvt_pk_f32_fp8(v[w], true);
    }
}

// ---------------- fused: bucket count + W prep + x->bf16 + x->fp8 ----------------
__global__ void k_prep(const int* __restrict__ edst, int* __restrict__ gcnt, int E,
                       int nEB, int NB,
                       const float* __restrict__ x, __hip_bfloat16* __restrict__ xb,
                       unsigned char* __restrict__ xf8, int nxelem,
                       const float* __restrict__ W, __hip_bfloat16* __restrict__ wt) {
    __shared__ int cnt[512];
    int b = blockIdx.x;
    int tid = threadIdx.x;
    if (b < nEB) {
        for (int i = tid; i < NB; i += 256) cnt[i] = 0;
        __syncthreads();
        int e0 = b * CHUNK;
        int eend = min(e0 + CHUNK, E);
        for (int i = e0 + tid; i < eend; i += 256) atomicAdd(&cnt[edst[i] >> 8], 1);
        __syncthreads();
        for (int i = tid; i < NB; i += 256) if (cnt[i]) atomicAdd(&gcnt[i], cnt[i]);
    } else if (b < nEB + 256) {
        // wt layout: [half(2)][col_local(128)][k(256)] bf16, byte XOR-swizzled
        int i = (b - nEB) * 256 + tid;   // i = k*256 + col
        int k = i >> 8, col = i & 255;
        int half = col >> 7, cl = col & 127;
        int byte = half * 65536 + cl * 512 + ((2 * k) ^ ((cl & 7) << 4));
        wt[byte >> 1] = __float2bfloat16(W[i]);
    } else {
        int i = (b - nEB - 256) * 256 + tid;   // 8 elems/thread
        size_t e0 = (size_t)i * 8;
        if (e0 < (size_t)nxelem) {
            const float4* xf4 = (const float4*)x;
            float4 v0 = xf4[i * 2], v1 = xf4[i * 2 + 1];
            bf16x8 o;
            o[0] = f2bf(v0.x); o[1] = f2bf(v0.y); o[2] = f2bf(v0.z); o[3] = f2bf(v0.w);
            o[4] = f2bf(v1.x); o[5] = f2bf(v1.y); o[6] = f2bf(v1.z); o[7] = f2bf(v1.w);
            *(bf16x8*)(xb + e0) = o;
            unsigned w0 = 0, w1 = 0;
            w0 = __builtin_amdgcn_cvt_pk_fp8_f32(v0.x, v0.y, w0, false);
            w0 = __builtin_amdgcn_cvt_pk_fp8_f32(v0.z, v0.w, w0, true);
            w1 = __builtin_amdgcn_cvt_pk_fp8_f32(v1.x, v1.y, w1, false);
            w1 = __builtin_amdgcn_cvt_pk_fp8_f32(v1.z, v1.w, w1, true);
            u32x2 pk; pk[0] = w0; pk[1] = w1;
            *(u32x2*)(xf8 + e0) = pk;
        }
    }
}

// ---------------- one-block parallel scan over buckets ----------------
__global__ void k_scan_nb(const int* __restrict__ gcnt, int* __restrict__ gbase,
                          int* __restrict__ gcur, int NB) {
    __shared__ int tmp[512];
    int t = threadIdx.x;
    int v = (t < NB) ? gcnt[t] : 0;
    tmp[t] = v;
    __syncthreads();
    for (int off = 1; off < 512; off <<= 1) {
        int add = (t >= off) ? tmp[t - off] : 0;
        __syncthreads();
        tmp[t] += add;
        __syncthreads();
    }
    int excl = tmp[t] - v;
    if (t < NB) { gbase[t] = excl; gcur[t] = excl; }
    if (t == 511) gbase[NB] = tmp[511];
}

// ---------------- pass A2: packed (src<<8|dstlo) pairs, 2048-edge chunks ----------------
__global__ void k_binA_write(const int* __restrict__ esrc, const int* __restrict__ edst,
                             int* __restrict__ gcur, unsigned int* __restrict__ pairs,
                             int E, int NB) {
    __shared__ int cnt[512];
    __shared__ int base[512];
    int t = threadIdx.x;
    for (int b = t; b < NB; b += 256) cnt[b] = 0;
    __syncthreads();
    int e0 = blockIdx.x * CHUNK2;
    int eend = min(e0 + CHUNK2, E);
    for (int i = e0 + t; i < eend; i += 256) atomicAdd(&cnt[edst[i] >> 8], 1);
    __syncthreads();
    for (int b = t; b < NB; b += 256) {
        base[b] = cnt[b] ? atomicAdd(&gcur[b], cnt[b]) : 0;
        cnt[b] = 0;
    }
    __syncthreads();
    for (int i = e0 + t; i < eend; i += 256) {
        int d = edst[i];
        int b = d >> 8;
        int idx = atomicAdd(&cnt[b], 1);
        pairs[base[b] + idx] = ((unsigned)esrc[i] << 8) | (unsigned)(d & 255);
    }
}

// ---------------- pass B: one block per bucket -> offs + csr ----------------
__global__ void k_binB(const unsigned int* __restrict__ pairs, const int* __restrict__ gbase,
                       int* __restrict__ offs, int* __restrict__ csr, int n) {
    __shared__ int cnt[256];
    __shared__ int tmp[256];
    int t = threadIdx.x;
    int b = blockIdx.x;
    int node0 = b << 8;
    cnt[t] = 0;
    __syncthreads();
    int beg = gbase[b], end = gbase[b + 1];
    for (int i = beg + t; i < end; i += 256) atomicAdd(&cnt[pairs[i] & 255], 1);
    __syncthreads();
    int v = cnt[t];
    tmp[t] = v;
    __syncthreads();
    for (int off = 1; off < 256; off <<= 1) {
        int add = (t >= off) ? tmp[t - off] : 0;
        __syncthreads();
        tmp[t] += add;
        __syncthreads();
    }
    int excl = tmp[t] - v;
    int node = node0 + t;
    if (node <= n) offs[node] = beg + excl;
    cnt[t] = beg + excl;
    __syncthreads();
    for (int i = beg + t; i < end; i += 256) {
        unsigned p = pairs[i];
        int slot = atomicAdd(&cnt[p & 255], 1);
        csr[slot] = (int)(p >> 8);
    }
}

// ---------------- aggregate: fp8 gather, one wave per node, 8 groups x 8 lanes x 16B ----------------
// One wave-level load instruction covers 8 edges x 128B (vs 4 edges before) ->
// half the L2 requests per edge. Depth-4 main + predicated 3-tail.
__global__ __launch_bounds__(256) void k_aggregate(const unsigned char* __restrict__ xf8,
                                                   const __hip_bfloat16* __restrict__ xb,
                                                   const int* __restrict__ offs,
                                                   const int* __restrict__ csr,
                                                   __hip_bfloat16* __restrict__ aggb, int n) {
    int tid = threadIdx.x;
    int node = blockIdx.x * 4 + (tid >> 6);
    if (node >= n) return;
    int lane = tid & 63;
    int g = lane >> 3;         // 0..7
    int l8 = lane & 7;         // 16B chunk within 128B row
    int beg = offs[node], end = offs[node + 1];
    int d = end - beg;
    const char* xbase = (const char*)xf8;    // row = src*128 bytes
    unsigned loff = (unsigned)(l8 << 4);

    f32x2 acc[8];   // dims 16*l8 + [0..15]
#pragma unroll
    for (int i = 0; i < 8; i++) acc[i] = (f32x2){0.f, 0.f};

    int j = beg + g;
    for (; j + 24 < end; j += 32) {   // 4 edges per group (stride 8)
        u32x4 v0 = *(const u32x4*)(xbase + (((unsigned)csr[j] << 7) + loff));
        u32x4 v1 = *(const u32x4*)(xbase + (((unsigned)csr[j + 8] << 7) + loff));
        u32x4 v2 = *(const u32x4*)(xbase + (((unsigned)csr[j + 16] << 7) + loff));
        u32x4 v3 = *(const u32x4*)(xbase + (((unsigned)csr[j + 24] << 7) + loff));
        accumf8x16(acc, v0); accumf8x16(acc, v1); accumf8x16(acc, v2); accumf8x16(acc, v3);
    }
    {   // tail: up to 3 edges per group, loads issued before consuming
        u32x4 z = (u32x4){0, 0, 0, 0};
        u32x4 t0 = z, t1 = z, t2 = z;
        if (j < end)      t0 = *(const u32x4*)(xbase + (((unsigned)csr[j] << 7) + loff));
        if (j + 8 < end)  t1 = *(const u32x4*)(xbase + (((unsigned)csr[j + 8] << 7) + loff));
        if (j + 16 < end) t2 = *(const u32x4*)(xbase + (((unsigned)csr[j + 16] << 7) + loff));
        accumf8x16(acc, t0); accumf8x16(acc, t1); accumf8x16(acc, t2);
    }

    // reduce across the 8 groups
#pragma unroll
    for (int u = 0; u < 8; u++) {
        float a = acc[u].x, b = acc[u].y;
        a += __shfl_xor(a, 8);  b += __shfl_xor(b, 8);
        a += __shfl_xor(a, 16); b += __shfl_xor(b, 16);
        a += __shfl_xor(a, 32); b += __shfl_xor(b, 32);
        acc[u].x = a; acc[u].y = b;
    }

    if (g == 0) {   // lanes 0..7: lane l8 owns dims 16*l8..16*l8+15
        bf16x8 o0, o1;
        if (d > 0) {
            float inv = 1.0f / (float)d;
#pragma unroll
            for (int i = 0; i < 4; i++) {
                o0[2 * i]     = f2bf(acc[i].x * inv);
                o0[2 * i + 1] = f2bf(acc[i].y * inv);
                o1[2 * i]     = f2bf(acc[4 + i].x * inv);
                o1[2 * i + 1] = f2bf(acc[4 + i].y * inv);
            }
        } else {
            const __hip_bfloat16* xrow = xb + (size_t)node * 128 + l8 * 16;
            o0 = *(const bf16x8*)xrow;
            o1 = *(const bf16x8*)(xrow + 8);
        }
        __hip_bfloat16* orow = aggb + (size_t)node * 128 + l8 * 16;
        *(bf16x8*)orow = o0;
        *(bf16x8*)(orow + 8) = o1;
    }
}

// ---------------- GEMM (R8-proven): BM=256, BN=128 by blockIdx, 2 blocks/CU ----------------
__global__ __launch_bounds__(256, 2) void k_gemm(const __hip_bfloat16* __restrict__ xb,
                                                 const __hip_bfloat16* __restrict__ aggb,
                                                 const __hip_bfloat16* __restrict__ wt,
                                                 const float* __restrict__ bias,
                                                 float* __restrict__ out, int n) {
    __shared__ uint4 lds4[4096];   // 64KB: one W half, swizzled [col][k]
    int tid = threadIdx.x;
    int half = blockIdx.x & 1;
    int tile = blockIdx.x >> 1;
    int row0 = tile * 256;

    const uint4* src = (const uint4*)((const char*)wt + half * 65536);
    for (int i = tid; i < 4096; i += 256) lds4[i] = src[i];
    __syncthreads();

    int wave = tid >> 6, lane = tid & 63;
    int colb = lane & 15, kgrp = lane >> 4;
    int swz = (colb & 7) << 4;
    int wrow0 = row0 + wave * 64;

    const bf16x8* hx[4];
    const bf16x8* hg[4];
#pragma unroll
    for (int m = 0; m < 4; m++) {
        int r = wrow0 + m * 16 + colb;
        int ar = r < n ? r : (n - 1);
        hx[m] = (const bf16x8*)(xb + (size_t)ar * 128);
        hg[m] = (const bf16x8*)(aggb + (size_t)ar * 128);
    }

    f32x4 acc[4][8];
#pragma unroll
    for (int m = 0; m < 4; m++)
#pragma unroll
        for (int nf = 0; nf < 8; nf++) acc[m][nf] = (f32x4){0.f, 0.f, 0.f, 0.f};

    const char* ldsb = (const char*)lds4;
#pragma unroll
    for (int ks = 0; ks < 8; ks++) {
        bf16x8 a[4];
#pragma unroll
        for (int m = 0; m < 4; m++)
            a[m] = (ks < 4) ? hx[m][kgrp + ks * 4] : hg[m][kgrp + (ks - 4) * 4];
        int kbyte = (kgrp * 16 + ks * 64) ^ swz;
#pragma unroll
        for (int nf = 0; nf < 8; nf++) {
            bf16x8 bfrag = *(const bf16x8*)(ldsb + (nf * 16 + colb) * 512 + kbyte);
#pragma unroll
            for (int m = 0; m < 4; m++)
                acc[m][nf] = __builtin_amdgcn_mfma_f32_16x16x32_bf16(bfrag, a[m], acc[m][nf], 0, 0, 0);
        }
    }

    // out row = wrow0 + m*16 + colb ; out col = half*128 + nf*16 + kgrp*4 + i
#pragma unroll
    for (int m = 0; m < 4; m++) {
        int r = wrow0 + m * 16 + colb;
        if (r < n) {
            float* orow = out + (size_t)r * 256 + half * 128;
#pragma unroll
            for (int nf = 0; nf < 8; nf++) {
                int c0 = nf * 16 + kgrp * 4;
                f32x4 bv = *(const f32x4*)(bias + half * 128 + c0);
                f32x4 v = acc[m][nf] + bv;
#pragma unroll
                for (int i = 0; i < 4; i++) v[i] = v[i] > 0.f ? v[i] : 0.f;
                *(f32x4*)(orow + c0) = v;
            }
        }
    }
}

extern "C" void kernel_launch(void* const* d_in, const int* in_sizes, int n_in,
                              void* d_out, int out_size, void* d_ws, size_t ws_size,
                              hipStream_t stream) {
    const float* x    = (const float*)d_in[0];
    const int*   esrc = (const int*)d_in[1];
    const int*   edst = (const int*)d_in[2];
    const float* W    = (const float*)d_in[3];
    const float* bias = (const float*)d_in[4];
    float* out = (float*)d_out;

    int n = in_sizes[0] / IN_DIM;   // 100000
    int E = in_sizes[1];            // 1600000
    int nxelem = n * IN_DIM;
    int NB = (n + 255) >> 8;        // 391

    char* p = (char*)d_ws;
    auto alloc = [&](size_t bytes) {
        char* r = p;
        p += (bytes + 255) & ~(size_t)255;
        return r;
    };
    int* gcnt  = (int*)alloc((size_t)NB * 4);
    int* gbase = (int*)alloc((size_t)(NB + 1) * 4);
    int* gcur  = (int*)alloc((size_t)NB * 4);
    int* offs  = (int*)alloc((size_t)(n + 1) * 4);
    unsigned int* pairs = (unsigned int*)alloc((size_t)E * 4);
    int* csr   = (int*)alloc((size_t)E * 4);
    __hip_bfloat16* wt   = (__hip_bfloat16*)alloc((size_t)65536 * 2);
    __hip_bfloat16* xb   = (__hip_bfloat16*)alloc((size_t)nxelem * 2);
    __hip_bfloat16* aggb = (__hip_bfloat16*)alloc((size_t)nxelem * 2);
    unsigned char* xf8   = (unsigned char*)alloc((size_t)nxelem);

    int nEB = (E + CHUNK - 1) / CHUNK;           // 391 (count pass)
    int nEB2 = (E + CHUNK2 - 1) / CHUNK2;        // 782 (write pass)
    int xcastB = (nxelem / 8 + 255) / 256;       // 6250

    hipMemsetAsync(gcnt, 0, (size_t)NB * 4, stream);
    k_prep<<<nEB + 256 + xcastB, 256, 0, stream>>>(edst, gcnt, E, nEB, NB,
                                                   x, xb, xf8, nxelem, W, wt);
    k_scan_nb<<<1, 512, 0, stream>>>(gcnt, gbase, gcur, NB);
    k_binA_write<<<nEB2, 256, 0, stream>>>(esrc, edst, gcur, pairs, E, NB);
    k_binB<<<NB, 256, 0, stream>>>(pairs, gbase, offs, csr, n);
    k_aggregate<<<(n + 3) / 4, 256, 0, stream>>>(xf8, xb, offs, csr, aggb, n);
    k_gemm<<<((n + 255) / 256) * 2, 256, 0, stream>>>(xb, aggb, wt, bias, out, n);
}

// Round 12
// 157.625 us; speedup vs baseline: 1.2047x; 1.1858x over previous
//
#include <hip/hip_runtime.h>
#include <hip/hip_bf16.h>

typedef __attribute__((ext_vector_type(8))) short bf16x8;
typedef __attribute__((ext_vector_type(4))) float f32x4;
typedef __attribute__((ext_vector_type(2))) float f32x2;
typedef __attribute__((ext_vector_type(2))) unsigned int u32x2;

#define IN_DIM 128
#define OUT_DIM 256
#define CHUNK 4096

__device__ __forceinline__ short f2bf(float f) {
    __hip_bfloat16 t = __float2bfloat16(f);
    return __builtin_bit_cast(short, t);
}

// decode 8 fp8 (u32x2) -> accumulate into 4x f32x2
__device__ __forceinline__ void accumf8(f32x2* a, u32x2 v) {
    f32x2 p0 = __builtin_amdgcn_cvt_pk_f32_fp8(v[0], false);
    f32x2 p1 = __builtin_amdgcn_cvt_pk_f32_fp8(v[0], true);
    f32x2 p2 = __builtin_amdgcn_cvt_pk_f32_fp8(v[1], false);
    f32x2 p3 = __builtin_amdgcn_cvt_pk_f32_fp8(v[1], true);
    a[0] += p0; a[1] += p1; a[2] += p2; a[3] += p3;
}

// ---------------- fused: bucket count + W prep + x->bf16 + x->fp8 (R8-exact) ----------------
__global__ void k_prep(const int* __restrict__ edst, int* __restrict__ gcnt, int E,
                       int nEB, int NB,
                       const float* __restrict__ x, __hip_bfloat16* __restrict__ xb,
                       unsigned char* __restrict__ xf8, int nxelem,
                       const float* __restrict__ W, __hip_bfloat16* __restrict__ wt) {
    __shared__ int cnt[512];
    int b = blockIdx.x;
    int tid = threadIdx.x;
    if (b < nEB) {
        for (int i = tid; i < NB; i += 256) cnt[i] = 0;
        __syncthreads();
        int e0 = b * CHUNK;
        int eend = min(e0 + CHUNK, E);
        for (int i = e0 + tid; i < eend; i += 256) atomicAdd(&cnt[edst[i] >> 8], 1);
        __syncthreads();
        for (int i = tid; i < NB; i += 256) if (cnt[i]) atomicAdd(&gcnt[i], cnt[i]);
    } else if (b < nEB + 256) {
        // wt layout: [half(2)][col_local(128)][k(256)] bf16, byte XOR-swizzled
        int i = (b - nEB) * 256 + tid;   // i = k*256 + col
        int k = i >> 8, col = i & 255;
        int half = col >> 7, cl = col & 127;
        int byte = half * 65536 + cl * 512 + ((2 * k) ^ ((cl & 7) << 4));
        wt[byte >> 1] = __float2bfloat16(W[i]);
    } else {
        int i = (b - nEB - 256) * 256 + tid;   // 8 elems/thread
        size_t e0 = (size_t)i * 8;
        if (e0 < (size_t)nxelem) {
            const float4* xf4 = (const float4*)x;
            float4 v0 = xf4[i * 2], v1 = xf4[i * 2 + 1];
            bf16x8 o;
            o[0] = f2bf(v0.x); o[1] = f2bf(v0.y); o[2] = f2bf(v0.z); o[3] = f2bf(v0.w);
            o[4] = f2bf(v1.x); o[5] = f2bf(v1.y); o[6] = f2bf(v1.z); o[7] = f2bf(v1.w);
            *(bf16x8*)(xb + e0) = o;
            unsigned w0 = 0, w1 = 0;
            w0 = __builtin_amdgcn_cvt_pk_fp8_f32(v0.x, v0.y, w0, false);
            w0 = __builtin_amdgcn_cvt_pk_fp8_f32(v0.z, v0.w, w0, true);
            w1 = __builtin_amdgcn_cvt_pk_fp8_f32(v1.x, v1.y, w1, false);
            w1 = __builtin_amdgcn_cvt_pk_fp8_f32(v1.z, v1.w, w1, true);
            u32x2 pk; pk[0] = w0; pk[1] = w1;
            *(u32x2*)(xf8 + e0) = pk;
        }
    }
}

// ---------------- one-block parallel scan over buckets ----------------
__global__ void k_scan_nb(const int* __restrict__ gcnt, int* __restrict__ gbase,
                          int* __restrict__ gcur, int NB) {
    __shared__ int tmp[512];
    int t = threadIdx.x;
    int v = (t < NB) ? gcnt[t] : 0;
    tmp[t] = v;
    __syncthreads();
    for (int off = 1; off < 512; off <<= 1) {
        int add = (t >= off) ? tmp[t - off] : 0;
        __syncthreads();
        tmp[t] += add;
        __syncthreads();
    }
    int excl = tmp[t] - v;
    if (t < NB) { gbase[t] = excl; gcur[t] = excl; }
    if (t == 511) gbase[NB] = tmp[511];
}

// ---------------- pass A2: packed (src<<8|dstlo) pairs, 4096-edge chunks (R8-exact) ----------------
__global__ void k_binA_write(const int* __restrict__ esrc, const int* __restrict__ edst,
                             int* __restrict__ gcur, unsigned int* __restrict__ pairs,
                             int E, int NB) {
    __shared__ int cnt[512];
    __shared__ int base[512];
    int t = threadIdx.x;
    for (int b = t; b < NB; b += 256) cnt[b] = 0;
    __syncthreads();
    int e0 = blockIdx.x * CHUNK;
    int eend = min(e0 + CHUNK, E);
    for (int i = e0 + t; i < eend; i += 256) atomicAdd(&cnt[edst[i] >> 8], 1);
    __syncthreads();
    for (int b = t; b < NB; b += 256) {
        base[b] = cnt[b] ? atomicAdd(&gcur[b], cnt[b]) : 0;
        cnt[b] = 0;
    }
    __syncthreads();
    for (int i = e0 + t; i < eend; i += 256) {
        int d = edst[i];
        int b = d >> 8;
        int idx = atomicAdd(&cnt[b], 1);
        pairs[base[b] + idx] = ((unsigned)esrc[i] << 8) | (unsigned)(d & 255);
    }
}

// ---------------- pass B: one block per bucket -> offs + csr ----------------
__global__ void k_binB(const unsigned int* __restrict__ pairs, const int* __restrict__ gbase,
                       int* __restrict__ offs, int* __restrict__ csr, int n) {
    __shared__ int cnt[256];
    __shared__ int tmp[256];
    int t = threadIdx.x;
    int b = blockIdx.x;
    int node0 = b << 8;
    cnt[t] = 0;
    __syncthreads();
    int beg = gbase[b], end = gbase[b + 1];
    for (int i = beg + t; i < end; i += 256) atomicAdd(&cnt[pairs[i] & 255], 1);
    __syncthreads();
    int v = cnt[t];
    tmp[t] = v;
    __syncthreads();
    for (int off = 1; off < 256; off <<= 1) {
        int add = (t >= off) ? tmp[t - off] : 0;
        __syncthreads();
        tmp[t] += add;
        __syncthreads();
    }
    int excl = tmp[t] - v;
    int node = node0 + t;
    if (node <= n) offs[node] = beg + excl;
    cnt[t] = beg + excl;
    __syncthreads();
    for (int i = beg + t; i < end; i += 256) {
        unsigned p = pairs[i];
        int slot = atomicAdd(&cnt[p & 255], 1);
        csr[slot] = (int)(p >> 8);
    }
}

// ---------------- aggregate (R8-exact): fp8 gather, 4 groups x 16 lanes x 8B ----------------
__global__ __launch_bounds__(256) void k_aggregate(const unsigned char* __restrict__ xf8,
                                                   const __hip_bfloat16* __restrict__ xb,
                                                   const int* __restrict__ offs,
                                                   const int* __restrict__ csr,
                                                   __hip_bfloat16* __restrict__ aggb, int n) {
    int tid = threadIdx.x;
    int node = blockIdx.x * 4 + (tid >> 6);
    if (node >= n) return;
    int lane = tid & 63;
    int g = lane >> 4;         // 0..3
    int l = lane & 15;         // 8B chunk within 128B row
    int beg = offs[node], end = offs[node + 1];
    int d = end - beg;
    const char* xbase = (const char*)xf8;    // row = src*128 bytes
    unsigned loff = (unsigned)(l << 3);

    f32x2 acc[4];   // dims 8l .. 8l+7
#pragma unroll
    for (int i = 0; i < 4; i++) acc[i] = (f32x2){0.f, 0.f};

    int j = beg + g;
    for (; j + 12 < end; j += 16) {
        u32x2 v0 = *(const u32x2*)(xbase + (((unsigned)csr[j] << 7) + loff));
        u32x2 v1 = *(const u32x2*)(xbase + (((unsigned)csr[j + 4] << 7) + loff));
        u32x2 v2 = *(const u32x2*)(xbase + (((unsigned)csr[j + 8] << 7) + loff));
        u32x2 v3 = *(const u32x2*)(xbase + (((unsigned)csr[j + 12] << 7) + loff));
        accumf8(acc, v0); accumf8(acc, v1); accumf8(acc, v2); accumf8(acc, v3);
    }
    {
        u32x2 z = (u32x2){0, 0};
        u32x2 t0 = z, t1 = z, t2 = z;
        if (j < end)     t0 = *(const u32x2*)(xbase + (((unsigned)csr[j] << 7) + loff));
        if (j + 4 < end) t1 = *(const u32x2*)(xbase + (((unsigned)csr[j + 4] << 7) + loff));
        if (j + 8 < end) t2 = *(const u32x2*)(xbase + (((unsigned)csr[j + 8] << 7) + loff));
        accumf8(acc, t0); accumf8(acc, t1); accumf8(acc, t2);
    }

#pragma unroll
    for (int u = 0; u < 4; u++) {
        float a = acc[u].x, b = acc[u].y;
        a += __shfl_xor(a, 16); b += __shfl_xor(b, 16);
        a += __shfl_xor(a, 32); b += __shfl_xor(b, 32);
        acc[u].x = a; acc[u].y = b;
    }

    if (g == 0) {
        bf16x8 o;
        if (d > 0) {
            float inv = 1.0f / (float)d;
#pragma unroll
            for (int i = 0; i < 4; i++) {
                o[2 * i]     = f2bf(acc[i].x * inv);
                o[2 * i + 1] = f2bf(acc[i].y * inv);
            }
        } else {
            o = *(const bf16x8*)(xb + (size_t)node * 128 + l * 8);
        }
        *(bf16x8*)(aggb + (size_t)node * 128 + l * 8) = o;
    }
}

// ---------------- GEMM: BM=512, BN=128, 512 thr (8 waves), 64KB LDS -> 16 waves/CU ----------------
__global__ __launch_bounds__(512, 2) void k_gemm(const __hip_bfloat16* __restrict__ xb,
                                                 const __hip_bfloat16* __restrict__ aggb,
                                                 const __hip_bfloat16* __restrict__ wt,
                                                 const float* __restrict__ bias,
                                                 float* __restrict__ out, int n) {
    __shared__ uint4 lds4[4096];   // 64KB: one W half, swizzled [col][k]
    int tid = threadIdx.x;
    int half = blockIdx.x & 1;
    int tile = blockIdx.x >> 1;
    int row0 = tile * 512;

    const uint4* src = (const uint4*)((const char*)wt + half * 65536);
    for (int i = tid; i < 4096; i += 512) lds4[i] = src[i];
    __syncthreads();

    int wave = tid >> 6, lane = tid & 63;
    int colb = lane & 15, kgrp = lane >> 4;
    int swz = (colb & 7) << 4;
    int wrow0 = row0 + wave * 64;

    const bf16x8* hx[4];
    const bf16x8* hg[4];
#pragma unroll
    for (int m = 0; m < 4; m++) {
        int r = wrow0 + m * 16 + colb;
        int ar = r < n ? r : (n - 1);
        hx[m] = (const bf16x8*)(xb + (size_t)ar * 128);
        hg[m] = (const bf16x8*)(aggb + (size_t)ar * 128);
    }

    f32x4 acc[4][8];
#pragma unroll
    for (int m = 0; m < 4; m++)
#pragma unroll
        for (int nf = 0; nf < 8; nf++) acc[m][nf] = (f32x4){0.f, 0.f, 0.f, 0.f};

    const char* ldsb = (const char*)lds4;
#pragma unroll
    for (int ks = 0; ks < 8; ks++) {
        bf16x8 a[4];
#pragma unroll
        for (int m = 0; m < 4; m++)
            a[m] = (ks < 4) ? hx[m][kgrp + ks * 4] : hg[m][kgrp + (ks - 4) * 4];
        int kbyte = (kgrp * 16 + ks * 64) ^ swz;
#pragma unroll
        for (int nf = 0; nf < 8; nf++) {
            bf16x8 bfrag = *(const bf16x8*)(ldsb + (nf * 16 + colb) * 512 + kbyte);
#pragma unroll
            for (int m = 0; m < 4; m++)
                acc[m][nf] = __builtin_amdgcn_mfma_f32_16x16x32_bf16(bfrag, a[m], acc[m][nf], 0, 0, 0);
        }
    }

    // out row = wrow0 + m*16 + colb ; out col = half*128 + nf*16 + kgrp*4 + i
#pragma unroll
    for (int m = 0; m < 4; m++) {
        int r = wrow0 + m * 16 + colb;
        if (r < n) {
            float* orow = out + (size_t)r * 256 + half * 128;
#pragma unroll
            for (int nf = 0; nf < 8; nf++) {
                int c0 = nf * 16 + kgrp * 4;
                f32x4 bv = *(const f32x4*)(bias + half * 128 + c0);
                f32x4 v = acc[m][nf] + bv;
#pragma unroll
                for (int i = 0; i < 4; i++) v[i] = v[i] > 0.f ? v[i] : 0.f;
                *(f32x4*)(orow + c0) = v;
            }
        }
    }
}

extern "C" void kernel_launch(void* const* d_in, const int* in_sizes, int n_in,
                              void* d_out, int out_size, void* d_ws, size_t ws_size,
                              hipStream_t stream) {
    const float* x    = (const float*)d_in[0];
    const int*   esrc = (const int*)d_in[1];
    const int*   edst = (const int*)d_in[2];
    const float* W    = (const float*)d_in[3];
    const float* bias = (const float*)d_in[4];
    float* out = (float*)d_out;

    int n = in_sizes[0] / IN_DIM;   // 100000
    int E = in_sizes[1];            // 1600000
    int nxelem = n * IN_DIM;
    int NB = (n + 255) >> 8;        // 391

    char* p = (char*)d_ws;
    auto alloc = [&](size_t bytes) {
        char* r = p;
        p += (bytes + 255) & ~(size_t)255;
        return r;
    };
    int* gcnt  = (int*)alloc((size_t)NB * 4);
    int* gbase = (int*)alloc((size_t)(NB + 1) * 4);
    int* gcur  = (int*)alloc((size_t)NB * 4);
    int* offs  = (int*)alloc((size_t)(n + 1) * 4);
    unsigned int* pairs = (unsigned int*)alloc((size_t)E * 4);
    int* csr   = (int*)alloc((size_t)E * 4);
    __hip_bfloat16* wt   = (__hip_bfloat16*)alloc((size_t)65536 * 2);
    __hip_bfloat16* xb   = (__hip_bfloat16*)alloc((size_t)nxelem * 2);
    __hip_bfloat16* aggb = (__hip_bfloat16*)alloc((size_t)nxelem * 2);
    unsigned char* xf8   = (unsigned char*)alloc((size_t)nxelem);

    int nEB = (E + CHUNK - 1) / CHUNK;           // 391
    int xcastB = (nxelem / 8 + 255) / 256;       // 6250

    hipMemsetAsync(gcnt, 0, (size_t)NB * 4, stream);
    k_prep<<<nEB + 256 + xcastB, 256, 0, stream>>>(edst, gcnt, E, nEB, NB,
                                                   x, xb, xf8, nxelem, W, wt);
    k_scan_nb<<<1, 512, 0, stream>>>(gcnt, gbase, gcur, NB);
    k_binA_write<<<nEB, 256, 0, stream>>>(esrc, edst, gcur, pairs, E, NB);
    k_binB<<<NB, 256, 0, stream>>>(pairs, gbase, offs, csr, n);
    k_aggregate<<<(n + 3) / 4, 256, 0, stream>>>(xf8, xb, offs, csr, aggb, n);
    k_gemm<<<((n + 511) / 512) * 2, 512, 0, stream>>>(xb, aggb, wt, bias, out, n);
}

// Round 13
// 156.607 us; speedup vs baseline: 1.2126x; 1.0065x over previous
//
#include <hip/hip_runtime.h>
#include <hip/hip_bf16.h>

typedef __attribute__((ext_vector_type(8))) short bf16x8;
typedef __attribute__((ext_vector_type(4))) float f32x4;
typedef __attribute__((ext_vector_type(2))) float f32x2;
typedef __attribute__((ext_vector_type(2))) unsigned int u32x2;

#define IN_DIM 128
#define OUT_DIM 256
#define CHUNK 4096

__device__ __forceinline__ short f2bf(float f) {
    __hip_bfloat16 t = __float2bfloat16(f);
    return __builtin_bit_cast(short, t);
}

// decode 8 fp8 (u32x2) -> accumulate into 4x f32x2
__device__ __forceinline__ void accumf8(f32x2* a, u32x2 v) {
    f32x2 p0 = __builtin_amdgcn_cvt_pk_f32_fp8(v[0], false);
    f32x2 p1 = __builtin_amdgcn_cvt_pk_f32_fp8(v[0], true);
    f32x2 p2 = __builtin_amdgcn_cvt_pk_f32_fp8(v[1], false);
    f32x2 p3 = __builtin_amdgcn_cvt_pk_f32_fp8(v[1], true);
    a[0] += p0; a[1] += p1; a[2] += p2; a[3] += p3;
}

// ---------------- count only: per-bucket edge histogram (gates the scan) ----------------
__global__ void k_count(const int* __restrict__ edst, int* __restrict__ gcnt, int E, int NB) {
    __shared__ int cnt[512];
    int tid = threadIdx.x;
    for (int i = tid; i < NB; i += 256) cnt[i] = 0;
    __syncthreads();
    int e0 = blockIdx.x * CHUNK;
    int eend = min(e0 + CHUNK, E);
    for (int i = e0 + tid; i < eend; i += 256) atomicAdd(&cnt[edst[i] >> 8], 1);
    __syncthreads();
    for (int i = tid; i < NB; i += 256) if (cnt[i]) atomicAdd(&gcnt[i], cnt[i]);
}

// ---------------- one-block parallel scan over buckets ----------------
__global__ void k_scan_nb(const int* __restrict__ gcnt, int* __restrict__ gbase,
                          int* __restrict__ gcur, int NB) {
    __shared__ int tmp[512];
    int t = threadIdx.x;
    int v = (t < NB) ? gcnt[t] : 0;
    tmp[t] = v;
    __syncthreads();
    for (int off = 1; off < 512; off <<= 1) {
        int add = (t >= off) ? tmp[t - off] : 0;
        __syncthreads();
        tmp[t] += add;
        __syncthreads();
    }
    int excl = tmp[t] - v;
    if (t < NB) { gbase[t] = excl; gcur[t] = excl; }
    if (t == 511) gbase[NB] = tmp[511];
}

// ---------------- fused mid: binA_write + W prep + x->bf16 + x->fp8 ----------------
// blocks [0,nEB): binA_write; [nEB,nEB+256): wprep; rest: xcast.
// The cast work (off the binning critical path) overlaps the binning pass.
__global__ void k_mid(const int* __restrict__ esrc, const int* __restrict__ edst,
                      int* __restrict__ gcur, unsigned int* __restrict__ pairs,
                      int E, int nEB, int NB,
                      const float* __restrict__ x, __hip_bfloat16* __restrict__ xb,
                      unsigned char* __restrict__ xf8, int nxelem,
                      const float* __restrict__ W, __hip_bfloat16* __restrict__ wt) {
    __shared__ int cnt[512];
    __shared__ int base[512];
    int b = blockIdx.x;
    int t = threadIdx.x;
    if (b < nEB) {
        for (int i = t; i < NB; i += 256) cnt[i] = 0;
        __syncthreads();
        int e0 = b * CHUNK;
        int eend = min(e0 + CHUNK, E);
        for (int i = e0 + t; i < eend; i += 256) atomicAdd(&cnt[edst[i] >> 8], 1);
        __syncthreads();
        for (int i = t; i < NB; i += 256) {
            base[i] = cnt[i] ? atomicAdd(&gcur[i], cnt[i]) : 0;
            cnt[i] = 0;
        }
        __syncthreads();
        for (int i = e0 + t; i < eend; i += 256) {
            int d = edst[i];
            int bk = d >> 8;
            int idx = atomicAdd(&cnt[bk], 1);
            pairs[base[bk] + idx] = ((unsigned)esrc[i] << 8) | (unsigned)(d & 255);
        }
    } else if (b < nEB + 256) {
        // wt layout: [half(2)][col_local(128)][k(256)] bf16, byte XOR-swizzled
        int i = (b - nEB) * 256 + t;   // i = k*256 + col
        int k = i >> 8, col = i & 255;
        int half = col >> 7, cl = col & 127;
        int byte = half * 65536 + cl * 512 + ((2 * k) ^ ((cl & 7) << 4));
        wt[byte >> 1] = __float2bfloat16(W[i]);
    } else {
        int i = (b - nEB - 256) * 256 + t;   // 8 elems/thread
        size_t e0 = (size_t)i * 8;
        if (e0 < (size_t)nxelem) {
            const float4* xf4 = (const float4*)x;
            float4 v0 = xf4[i * 2], v1 = xf4[i * 2 + 1];
            bf16x8 o;
            o[0] = f2bf(v0.x); o[1] = f2bf(v0.y); o[2] = f2bf(v0.z); o[3] = f2bf(v0.w);
            o[4] = f2bf(v1.x); o[5] = f2bf(v1.y); o[6] = f2bf(v1.z); o[7] = f2bf(v1.w);
            *(bf16x8*)(xb + e0) = o;
            unsigned w0 = 0, w1 = 0;
            w0 = __builtin_amdgcn_cvt_pk_fp8_f32(v0.x, v0.y, w0, false);
            w0 = __builtin_amdgcn_cvt_pk_fp8_f32(v0.z, v0.w, w0, true);
            w1 = __builtin_amdgcn_cvt_pk_fp8_f32(v1.x, v1.y, w1, false);
            w1 = __builtin_amdgcn_cvt_pk_fp8_f32(v1.z, v1.w, w1, true);
            u32x2 pk; pk[0] = w0; pk[1] = w1;
            *(u32x2*)(xf8 + e0) = pk;
        }
    }
}

// ---------------- pass B: one block per bucket -> offs + csr ----------------
__global__ void k_binB(const unsigned int* __restrict__ pairs, const int* __restrict__ gbase,
                       int* __restrict__ offs, int* __restrict__ csr, int n) {
    __shared__ int cnt[256];
    __shared__ int tmp[256];
    int t = threadIdx.x;
    int b = blockIdx.x;
    int node0 = b << 8;
    cnt[t] = 0;
    __syncthreads();
    int beg = gbase[b], end = gbase[b + 1];
    for (int i = beg + t; i < end; i += 256) atomicAdd(&cnt[pairs[i] & 255], 1);
    __syncthreads();
    int v = cnt[t];
    tmp[t] = v;
    __syncthreads();
    for (int off = 1; off < 256; off <<= 1) {
        int add = (t >= off) ? tmp[t - off] : 0;
        __syncthreads();
        tmp[t] += add;
        __syncthreads();
    }
    int excl = tmp[t] - v;
    int node = node0 + t;
    if (node <= n) offs[node] = beg + excl;
    cnt[t] = beg + excl;
    __syncthreads();
    for (int i = beg + t; i < end; i += 256) {
        unsigned p = pairs[i];
        int slot = atomicAdd(&cnt[p & 255], 1);
        csr[slot] = (int)(p >> 8);
    }
}

// ---------------- aggregate (R8-exact): fp8 gather, 4 groups x 16 lanes x 8B ----------------
__global__ __launch_bounds__(256) void k_aggregate(const unsigned char* __restrict__ xf8,
                                                   const __hip_bfloat16* __restrict__ xb,
                                                   const int* __restrict__ offs,
                                                   const int* __restrict__ csr,
                                                   __hip_bfloat16* __restrict__ aggb, int n) {
    int tid = threadIdx.x;
    int node = blockIdx.x * 4 + (tid >> 6);
    if (node >= n) return;
    int lane = tid & 63;
    int g = lane >> 4;         // 0..3
    int l = lane & 15;         // 8B chunk within 128B row
    int beg = offs[node], end = offs[node + 1];
    int d = end - beg;
    const char* xbase = (const char*)xf8;    // row = src*128 bytes
    unsigned loff = (unsigned)(l << 3);

    f32x2 acc[4];   // dims 8l .. 8l+7
#pragma unroll
    for (int i = 0; i < 4; i++) acc[i] = (f32x2){0.f, 0.f};

    int j = beg + g;
    for (; j + 12 < end; j += 16) {
        u32x2 v0 = *(const u32x2*)(xbase + (((unsigned)csr[j] << 7) + loff));
        u32x2 v1 = *(const u32x2*)(xbase + (((unsigned)csr[j + 4] << 7) + loff));
        u32x2 v2 = *(const u32x2*)(xbase + (((unsigned)csr[j + 8] << 7) + loff));
        u32x2 v3 = *(const u32x2*)(xbase + (((unsigned)csr[j + 12] << 7) + loff));
        accumf8(acc, v0); accumf8(acc, v1); accumf8(acc, v2); accumf8(acc, v3);
    }
    {
        u32x2 z = (u32x2){0, 0};
        u32x2 t0 = z, t1 = z, t2 = z;
        if (j < end)     t0 = *(const u32x2*)(xbase + (((unsigned)csr[j] << 7) + loff));
        if (j + 4 < end) t1 = *(const u32x2*)(xbase + (((unsigned)csr[j + 4] << 7) + loff));
        if (j + 8 < end) t2 = *(const u32x2*)(xbase + (((unsigned)csr[j + 8] << 7) + loff));
        accumf8(acc, t0); accumf8(acc, t1); accumf8(acc, t2);
    }

#pragma unroll
    for (int u = 0; u < 4; u++) {
        float a = acc[u].x, b = acc[u].y;
        a += __shfl_xor(a, 16); b += __shfl_xor(b, 16);
        a += __shfl_xor(a, 32); b += __shfl_xor(b, 32);
        acc[u].x = a; acc[u].y = b;
    }

    if (g == 0) {
        bf16x8 o;
        if (d > 0) {
            float inv = 1.0f / (float)d;
#pragma unroll
            for (int i = 0; i < 4; i++) {
                o[2 * i]     = f2bf(acc[i].x * inv);
                o[2 * i + 1] = f2bf(acc[i].y * inv);
            }
        } else {
            o = *(const bf16x8*)(xb + (size_t)node * 128 + l * 8);
        }
        *(bf16x8*)(aggb + (size_t)node * 128 + l * 8) = o;
    }
}

// ---------------- GEMM (R12-exact): BM=512, BN=128, 512 thr, 64KB LDS -> 16 waves/CU ----------------
__global__ __launch_bounds__(512, 2) void k_gemm(const __hip_bfloat16* __restrict__ xb,
                                                 const __hip_bfloat16* __restrict__ aggb,
                                                 const __hip_bfloat16* __restrict__ wt,
                                                 const float* __restrict__ bias,
                                                 float* __restrict__ out, int n) {
    __shared__ uint4 lds4[4096];   // 64KB: one W half, swizzled [col][k]
    int tid = threadIdx.x;
    int half = blockIdx.x & 1;
    int tile = blockIdx.x >> 1;
    int row0 = tile * 512;

    const uint4* src = (const uint4*)((const char*)wt + half * 65536);
    for (int i = tid; i < 4096; i += 512) lds4[i] = src[i];
    __syncthreads();

    int wave = tid >> 6, lane = tid & 63;
    int colb = lane & 15, kgrp = lane >> 4;
    int swz = (colb & 7) << 4;
    int wrow0 = row0 + wave * 64;

    const bf16x8* hx[4];
    const bf16x8* hg[4];
#pragma unroll
    for (int m = 0; m < 4; m++) {
        int r = wrow0 + m * 16 + colb;
        int ar = r < n ? r : (n - 1);
        hx[m] = (const bf16x8*)(xb + (size_t)ar * 128);
        hg[m] = (const bf16x8*)(aggb + (size_t)ar * 128);
    }

    f32x4 acc[4][8];
#pragma unroll
    for (int m = 0; m < 4; m++)
#pragma unroll
        for (int nf = 0; nf < 8; nf++) acc[m][nf] = (f32x4){0.f, 0.f, 0.f, 0.f};

    const char* ldsb = (const char*)lds4;
#pragma unroll
    for (int ks = 0; ks < 8; ks++) {
        bf16x8 a[4];
#pragma unroll
        for (int m = 0; m < 4; m++)
            a[m] = (ks < 4) ? hx[m][kgrp + ks * 4] : hg[m][kgrp + (ks - 4) * 4];
        int kbyte = (kgrp * 16 + ks * 64) ^ swz;
#pragma unroll
        for (int nf = 0; nf < 8; nf++) {
            bf16x8 bfrag = *(const bf16x8*)(ldsb + (nf * 16 + colb) * 512 + kbyte);
#pragma unroll
            for (int m = 0; m < 4; m++)
                acc[m][nf] = __builtin_amdgcn_mfma_f32_16x16x32_bf16(bfrag, a[m], acc[m][nf], 0, 0, 0);
        }
    }

    // out row = wrow0 + m*16 + colb ; out col = half*128 + nf*16 + kgrp*4 + i
#pragma unroll
    for (int m = 0; m < 4; m++) {
        int r = wrow0 + m * 16 + colb;
        if (r < n) {
            float* orow = out + (size_t)r * 256 + half * 128;
#pragma unroll
            for (int nf = 0; nf < 8; nf++) {
                int c0 = nf * 16 + kgrp * 4;
                f32x4 bv = *(const f32x4*)(bias + half * 128 + c0);
                f32x4 v = acc[m][nf] + bv;
#pragma unroll
                for (int i = 0; i < 4; i++) v[i] = v[i] > 0.f ? v[i] : 0.f;
                *(f32x4*)(orow + c0) = v;
            }
        }
    }
}

extern "C" void kernel_launch(void* const* d_in, const int* in_sizes, int n_in,
                              void* d_out, int out_size, void* d_ws, size_t ws_size,
                              hipStream_t stream) {
    const float* x    = (const float*)d_in[0];
    const int*   esrc = (const int*)d_in[1];
    const int*   edst = (const int*)d_in[2];
    const float* W    = (const float*)d_in[3];
    const float* bias = (const float*)d_in[4];
    float* out = (float*)d_out;

    int n = in_sizes[0] / IN_DIM;   // 100000
    int E = in_sizes[1];            // 1600000
    int nxelem = n * IN_DIM;
    int NB = (n + 255) >> 8;        // 391

    char* p = (char*)d_ws;
    auto alloc = [&](size_t bytes) {
        char* r = p;
        p += (bytes + 255) & ~(size_t)255;
        return r;
    };
    int* gcnt  = (int*)alloc((size_t)NB * 4);
    int* gbase = (int*)alloc((size_t)(NB + 1) * 4);
    int* gcur  = (int*)alloc((size_t)NB * 4);
    int* offs  = (int*)alloc((size_t)(n + 1) * 4);
    unsigned int* pairs = (unsigned int*)alloc((size_t)E * 4);
    int* csr   = (int*)alloc((size_t)E * 4);
    __hip_bfloat16* wt   = (__hip_bfloat16*)alloc((size_t)65536 * 2);
    __hip_bfloat16* xb   = (__hip_bfloat16*)alloc((size_t)nxelem * 2);
    __hip_bfloat16* aggb = (__hip_bfloat16*)alloc((size_t)nxelem * 2);
    unsigned char* xf8   = (unsigned char*)alloc((size_t)nxelem);

    int nEB = (E + CHUNK - 1) / CHUNK;           // 391
    int xcastB = (nxelem / 8 + 255) / 256;       // 6250

    hipMemsetAsync(gcnt, 0, (size_t)NB * 4, stream);
    k_count<<<nEB, 256, 0, stream>>>(edst, gcnt, E, NB);
    k_scan_nb<<<1, 512, 0, stream>>>(gcnt, gbase, gcur, NB);
    k_mid<<<nEB + 256 + xcastB, 256, 0, stream>>>(esrc, edst, gcur, pairs, E, nEB, NB,
                                                  x, xb, xf8, nxelem, W, wt);
    k_binB<<<NB, 256, 0, stream>>>(pairs, gbase, offs, csr, n);
    k_aggregate<<<(n + 3) / 4, 256, 0, stream>>>(xf8, xb, offs, csr, aggb, n);
    k_gemm<<<((n + 511) / 512) * 2, 512, 0, stream>>>(xb, aggb, wt, bias, out, n);
}